// Round 5
// baseline (117.058 us; speedup 1.0000x reference)
//
#include <hip/hip_runtime.h>
#include <hip/hip_bf16.h>
#include <cstdint>
#include <cstddef>

static constexpr int Bk  = 4;
static constexpr int N1k = 2048;
static constexpr int N2k = 8192;
static constexpr int Ck  = 288;
static constexpr int NSk = 32;

typedef __hip_bfloat16 bf16;

// ---------------------------------------------------------------------------
// K0 (fused): transpose support_features [B,C,N2] fp32 -> Ftr [B,N2,C] bf16
//            + pack support xyz/mask into float4 (blocks with cT==0)
//            + zero the global sums buffer (block x==0,cT==0,b==0)
// ---------------------------------------------------------------------------
__global__ void k_tr_pack(const float* __restrict__ F, const float* __restrict__ sxyz,
                          const float* __restrict__ smask, bf16* __restrict__ Ftr,
                          float4* __restrict__ pxyz, float* __restrict__ sums) {
  __shared__ float tile[32][33];
  int b  = blockIdx.z;
  int cT = blockIdx.y * 32, sT = blockIdx.x * 32;
  int tx = threadIdx.x, ty = threadIdx.y;  // 32 x 8
  const float* Fb = F + (size_t)b * Ck * N2k;
  #pragma unroll
  for (int j = 0; j < 32; j += 8)
    tile[ty + j][tx] = Fb[(size_t)(cT + ty + j) * N2k + sT + tx];

  if (cT == 0) {
    if (ty == 0) {                       // pack: 32 points per x-block
      int s = b * N2k + sT + tx;
      pxyz[s] = make_float4(sxyz[3 * s], sxyz[3 * s + 1], sxyz[3 * s + 2], smask[s]);
    }
    if (blockIdx.x == 0 && b == 0) {     // zero sums: 3*Bk*Ck floats
      int t = ty * 32 + tx;
      for (int i = t; i < 3 * Bk * Ck; i += 256) sums[i] = 0.f;
    }
  }

  __syncthreads();
  bf16* Ob = Ftr + (size_t)b * N2k * Ck;
  #pragma unroll
  for (int j = 0; j < 32; j += 8)
    Ob[(size_t)(sT + ty + j) * Ck + cT + tx] = __float2bfloat16(tile[tx][ty + j]);
}

// ---------------------------------------------------------------------------
// K1 (fused): ball query + aggregation. Block = 256 = 4 waves; wave w owns
// query n = (blockIdx>>2)*4+w of batch b = blockIdx&3 (XCD->batch pinning).
// Phase A (per wave, no block sync): scan support points 256/iter with
//   prefetch; finder lanes write idx + rel (and rel*fm) straight to LDS;
//   pad tail slots with firstIdx.
// Phase B (per wave, immediately): gather Ftr rows for its 32 neighbors.
//   Lane l owns channels {l, l+96, l+192} (axis l%3); lanes<32 additionally
//   {64+l, 160+l, 256+l} (axis (l+1)%3). Accumulate masked a1 and unmasked
//   a2; write U[b,n,c] = a1/fmsum (bf16).
// Phase C: block LDS reduce of per-(b,c) sums (S2, U, U^2) + 864 atomics.
// ---------------------------------------------------------------------------
__global__ __launch_bounds__(256, 4) void k_bq_agg(
    const float4* __restrict__ pxyz, const float* __restrict__ qxyz,
    const float* __restrict__ qmask, const bf16* __restrict__ Ftr,
    bf16* __restrict__ U, float* __restrict__ sums) {
  __shared__ int   sidx[4][NSk];
  __shared__ float srel[4][NSk][3];
  __shared__ float srelm[4][NSk][3];
  __shared__ float red[3 * Ck];

  int t = threadIdx.x;
  int w = t >> 6, lane = t & 63;
  int b = blockIdx.x & 3;
  int n = (blockIdx.x >> 2) * 4 + w;
  int q = b * N1k + n;

  for (int i = t; i < 3 * Ck; i += 256) red[i] = 0.f;
  __syncthreads();

  // ---- Phase A: ball query (wave-private) ----
  const float4* P = pxyz + (size_t)b * N2k;
  float qm = qmask[q];
  float qx = qxyz[q * 3 + 0], qy = qxyz[q * 3 + 1], qz = qxyz[q * 3 + 2];
  int cnt = 0, firstIdx = 0;

  if (qm > 0.f) {
    unsigned long long lmlt = (1ull << lane) - 1ull;
    float4 cur[4];
    #pragma unroll
    for (int u = 0; u < 4; ++u) cur[u] = P[u * 64 + lane];
    for (int s0 = 0; s0 < N2k && cnt < NSk; s0 += 256) {
      float4 nxt[4];
      #pragma unroll
      for (int u = 0; u < 4; ++u) {
        int sp = s0 + 256 + u * 64 + lane;
        sp = (sp < N2k) ? sp : 0;           // clamped, unconditional prefetch
        nxt[u] = P[sp];
      }
      #pragma unroll
      for (int u = 0; u < 4; ++u) {
        float dx = qx - cur[u].x, dy = qy - cur[u].y, dz = qz - cur[u].z;
        // match numpy association: (dx^2 + dy^2) + dz^2, no FMA contraction
        float d2 = __fadd_rn(__fadd_rn(__fmul_rn(dx, dx), __fmul_rn(dy, dy)),
                             __fmul_rn(dz, dz));
        bool valid = (d2 < 0.04f) && (cur[u].w > 0.f);
        unsigned long long m = __ballot(valid);
        if (cnt == 0 && m != 0ull) firstIdx = s0 + u * 64 + (int)__builtin_ctzll(m);
        int p = cnt + (int)__popcll(m & lmlt);
        if (valid && p < NSk) {
          sidx[w][p] = s0 + u * 64 + lane;
          float rx = (cur[u].x - qx) / 0.2f;
          float ry = (cur[u].y - qy) / 0.2f;
          float rz = (cur[u].z - qz) / 0.2f;
          srel[w][p][0] = rx;  srel[w][p][1] = ry;  srel[w][p][2] = rz;
          srelm[w][p][0] = rx; srelm[w][p][1] = ry; srelm[w][p][2] = rz;  // fm=1
        }
        cnt += (int)__popcll(m);
      }
      #pragma unroll
      for (int u = 0; u < 4; ++u) cur[u] = nxt[u];
    }
    if (cnt > NSk) cnt = NSk;
  }
  {  // pad tail slots with firstIdx (fm=0 if qm>0, else fm=1)
    float4 pf = P[firstIdx];
    float rx = (pf.x - qx) / 0.2f, ry = (pf.y - qy) / 0.2f, rz = (pf.z - qz) / 0.2f;
    float mx = (qm > 0.f) ? 0.f : rx;
    float my = (qm > 0.f) ? 0.f : ry;
    float mz = (qm > 0.f) ? 0.f : rz;
    for (int p = cnt + lane; p < NSk; p += 64) {
      sidx[w][p] = firstIdx;
      srel[w][p][0] = rx;  srel[w][p][1] = ry;  srel[w][p][2] = rz;
      srelm[w][p][0] = mx; srelm[w][p][1] = my; srelm[w][p][2] = mz;
    }
  }
  float finv = (qm > 0.f) ? ((cnt > 0) ? 1.f / (float)cnt : 0.f) : (1.f / 32.f);

  __threadfence_block();               // order wave-private LDS writes->reads
  __builtin_amdgcn_wave_barrier();

  // ---- Phase B: gather + aggregate (wave-private) ----
  const bf16* Fb = Ftr + (size_t)b * N2k * Ck;
  int aA = lane % 3;
  int aB = (lane + 1) % 3;             // axis of channel 64+lane (+96m)
  float a1A[3] = {0.f, 0.f, 0.f}, a2A[3] = {0.f, 0.f, 0.f};
  float a1B[3] = {0.f, 0.f, 0.f}, a2B[3] = {0.f, 0.f, 0.f};

  #pragma unroll 4
  for (int k = 0; k < NSk; ++k) {
    const bf16* row = Fb + (size_t)sidx[w][k] * Ck;
    float r  = srel[w][k][aA];
    float rm = srelm[w][k][aA];
    float f0 = __bfloat162float(row[lane]);
    float f1 = __bfloat162float(row[lane + 96]);
    float f2 = __bfloat162float(row[lane + 192]);
    a2A[0] = fmaf(f0, r, a2A[0]);
    a2A[1] = fmaf(f1, r, a2A[1]);
    a2A[2] = fmaf(f2, r, a2A[2]);
    a1A[0] = fmaf(f0, rm, a1A[0]);
    a1A[1] = fmaf(f1, rm, a1A[1]);
    a1A[2] = fmaf(f2, rm, a1A[2]);
    if (lane < 32) {
      float rb  = srel[w][k][aB];
      float rmb = srelm[w][k][aB];
      float g0 = __bfloat162float(row[64 + lane]);
      float g1 = __bfloat162float(row[160 + lane]);
      float g2 = __bfloat162float(row[256 + lane]);
      a2B[0] = fmaf(g0, rb, a2B[0]);
      a2B[1] = fmaf(g1, rb, a2B[1]);
      a2B[2] = fmaf(g2, rb, a2B[2]);
      a1B[0] = fmaf(g0, rmb, a1B[0]);
      a1B[1] = fmaf(g1, rmb, a1B[1]);
      a1B[2] = fmaf(g2, rmb, a1B[2]);
    }
  }

  bf16* Urow = U + (size_t)q * Ck;
  float u0 = a1A[0] * finv, u1 = a1A[1] * finv, u2 = a1A[2] * finv;
  Urow[lane]       = __float2bfloat16(u0);
  Urow[lane + 96]  = __float2bfloat16(u1);
  Urow[lane + 192] = __float2bfloat16(u2);
  atomicAdd(&red[lane],            a2A[0]);
  atomicAdd(&red[lane + 96],       a2A[1]);
  atomicAdd(&red[lane + 192],      a2A[2]);
  atomicAdd(&red[Ck + lane],       u0);
  atomicAdd(&red[Ck + lane + 96],  u1);
  atomicAdd(&red[Ck + lane + 192], u2);
  atomicAdd(&red[2 * Ck + lane],            u0 * u0);
  atomicAdd(&red[2 * Ck + lane + 96],       u1 * u1);
  atomicAdd(&red[2 * Ck + lane + 192],      u2 * u2);
  if (lane < 32) {
    float v0 = a1B[0] * finv, v1 = a1B[1] * finv, v2 = a1B[2] * finv;
    Urow[64 + lane]  = __float2bfloat16(v0);
    Urow[160 + lane] = __float2bfloat16(v1);
    Urow[256 + lane] = __float2bfloat16(v2);
    atomicAdd(&red[64 + lane],       a2B[0]);
    atomicAdd(&red[160 + lane],      a2B[1]);
    atomicAdd(&red[256 + lane],      a2B[2]);
    atomicAdd(&red[Ck + 64 + lane],  v0);
    atomicAdd(&red[Ck + 160 + lane], v1);
    atomicAdd(&red[Ck + 256 + lane], v2);
    atomicAdd(&red[2 * Ck + 64 + lane],  v0 * v0);
    atomicAdd(&red[2 * Ck + 160 + lane], v1 * v1);
    atomicAdd(&red[2 * Ck + 256 + lane], v2 * v2);
  }

  // ---- Phase C: global merge ----
  __syncthreads();
  for (int i = t; i < 3 * Ck; i += 256) {
    int arr = i / Ck, c = i - arr * Ck;
    atomicAdd(&sums[arr * (Bk * Ck) + b * Ck + c], red[i]);
  }
}

// ---------------------------------------------------------------------------
// K2 (fused): finalize + inline excite. Each block recomputes the tiny SE MLP
// from the completed sums (w1/w2 are L2-hot), then transposes its U tile
// [B,N1,C] bf16 -> out [B,C,N1] fp32 applying relu(scale*u + bias).
// ---------------------------------------------------------------------------
__global__ __launch_bounds__(256) void k_fin(
    const bf16* __restrict__ U, const float* __restrict__ sums,
    const float* __restrict__ w1, const float* __restrict__ w2,
    const float* __restrict__ gamma, const float* __restrict__ beta,
    float* __restrict__ out) {
  __shared__ float tile[32][33];
  __shared__ float gse[Bk][Ck];
  __shared__ float hid[Bk * 18];
  __shared__ float sA[32], sB[32];

  int b  = blockIdx.z;
  int cT = blockIdx.y * 32, nT = blockIdx.x * 32;
  int tx = threadIdx.x, ty = threadIdx.y;  // 32 x 8
  int t = ty * 32 + tx;

  const bf16* Ub = U + (size_t)b * N1k * Ck;
  #pragma unroll
  for (int j = 0; j < 32; j += 8)
    tile[ty + j][tx] = __bfloat162float(Ub[(size_t)(nT + ty + j) * Ck + cT + tx]);

  for (int i = t; i < Bk * Ck; i += 256) gse[i / Ck][i % Ck] = sums[i] * (1.f / 65536.f);
  __syncthreads();

  if (t < Bk * 18) {                   // hid = relu(gse @ w1.T)
    int bb = t / 18, h = t % 18;
    const float* w1r = w1 + h * Ck;
    float s = 0.f;
    #pragma unroll 4
    for (int c = 0; c < Ck; ++c) s = fmaf(gse[bb][c], w1r[c], s);
    hid[t] = s > 0.f ? s : 0.f;
  }
  __syncthreads();
  if (t < 32) {                        // excite + LN fold for this block's channels
    int c = cT + t;
    const float* sumU  = sums + Bk * Ck;
    const float* sumU2 = sums + 2 * Bk * Ck;
    float m = 0.f, m2 = 0.f, eb_my = 0.f;
    #pragma unroll
    for (int bb = 0; bb < Bk; ++bb) {
      float s = 0.f;
      #pragma unroll
      for (int h = 0; h < 18; ++h) s += hid[bb * 18 + h] * w2[c * 18 + h];
      float e = 1.f / (1.f + expf(-s));
      if (bb == b) eb_my = e;
      m  += e * sumU[bb * Ck + c];
      m2 += e * e * sumU2[bb * Ck + c];
    }
    float mean = m * (1.f / 8192.f);
    float var  = m2 * (1.f / 8192.f) - mean * mean;
    float rsig = rsqrtf(var + 1e-5f);
    float gc = gamma[c];
    sA[t] = gc * rsig * eb_my;
    sB[t] = beta[c] - gc * rsig * mean;
  }
  __syncthreads();

  float* Ob = out + (size_t)b * Ck * N1k;
  #pragma unroll
  for (int j = 0; j < 32; j += 8) {
    int c = cT + ty + j;
    float v = sA[ty + j] * tile[tx][ty + j] + sB[ty + j];
    Ob[(size_t)c * N1k + nT + tx] = v > 0.f ? v : 0.f;
  }
}

// ---------------------------------------------------------------------------
extern "C" void kernel_launch(void* const* d_in, const int* in_sizes, int n_in,
                              void* d_out, int out_size, void* d_ws, size_t ws_size,
                              hipStream_t stream) {
  const float* qxyz  = (const float*)d_in[0];
  const float* sxyz  = (const float*)d_in[1];
  const float* qm    = (const float*)d_in[2];
  const float* sm    = (const float*)d_in[3];
  const float* F     = (const float*)d_in[4];
  const float* w1    = (const float*)d_in[5];
  const float* w2    = (const float*)d_in[6];
  const float* gamma = (const float*)d_in[7];
  const float* beta  = (const float*)d_in[8];

  char* ws = (char*)d_ws;
  size_t off = 0;
  auto alloc = [&](size_t bytes) {
    off = (off + 255) & ~(size_t)255;
    void* p = ws + off;
    off += bytes;
    return p;
  };
  bf16*   Ftr  = (bf16*)  alloc(sizeof(bf16)   * (size_t)Bk * N2k * Ck);
  bf16*   U    = (bf16*)  alloc(sizeof(bf16)   * (size_t)Bk * N1k * Ck);
  float4* pxyz = (float4*)alloc(sizeof(float4) * (size_t)Bk * N2k);
  float*  sums = (float*) alloc(sizeof(float)  * 3 * Bk * Ck);

  k_tr_pack<<<dim3(N2k / 32, Ck / 32, Bk), dim3(32, 8), 0, stream>>>(F, sxyz, sm, Ftr,
                                                                     pxyz, sums);
  k_bq_agg<<<Bk * (N1k / 4), 256, 0, stream>>>(pxyz, qxyz, qm, Ftr, U, sums);
  k_fin<<<dim3(N1k / 32, Ck / 32, Bk), dim3(32, 8), 0, stream>>>(U, sums, w1, w2,
                                                                 gamma, beta,
                                                                 (float*)d_out);
}

// Round 6
// 91.454 us; speedup vs baseline: 1.2800x; 1.2800x over previous
//
#include <hip/hip_runtime.h>
#include <hip/hip_bf16.h>
#include <cstdint>
#include <cstddef>

static constexpr int Bk  = 4;
static constexpr int N1k = 2048;
static constexpr int N2k = 8192;
static constexpr int Ck  = 288;
static constexpr int NSk = 32;
static constexpr int TRB = (N2k / 32) * (Ck / 32) * Bk;   // 9216 transpose blocks

typedef __hip_bfloat16 bf16;

// ---------------------------------------------------------------------------
// K0 (heterogeneous grid): blocks [0,TRB) transpose support_features
// [B,C,N2] fp32 -> Ftr [B,N2,C] bf16 (+ block 0 zeroes sums); blocks
// [TRB, TRB+2048) run the masked ball query (wave per query, 4 pts/lane/iter
// with scalar prefetch). The two jobs are independent: BQ (latency-bound)
// overlaps the transpose's HBM stream.
// ---------------------------------------------------------------------------
__global__ __launch_bounds__(256) void k_pre(
    const float* __restrict__ F, const float* __restrict__ sxyz,
    const float* __restrict__ smask, const float* __restrict__ qxyz,
    const float* __restrict__ qmask, bf16* __restrict__ Ftr,
    int* __restrict__ idxArr, int* __restrict__ cntArr,
    float* __restrict__ sums) {
  __shared__ float tile[32][33];
  int t = threadIdx.x;

  if (blockIdx.x < TRB) {
    // ---- transpose part ----
    int i  = blockIdx.x;
    int sT = (i & 255) * 32;
    int yz = i >> 8;
    int cT = (yz % 9) * 32;
    int b  = yz / 9;
    int tx = t & 31, ty = t >> 5;      // 32 x 8
    const float* Fb = F + (size_t)b * Ck * N2k;
    #pragma unroll
    for (int j = 0; j < 32; j += 8)
      tile[ty + j][tx] = Fb[(size_t)(cT + ty + j) * N2k + sT + tx];
    if (i == 0) {
      for (int k = t; k < 3 * Bk * Ck; k += 256) sums[k] = 0.f;
    }
    __syncthreads();
    bf16* Ob = Ftr + (size_t)b * N2k * Ck;
    #pragma unroll
    for (int j = 0; j < 32; j += 8)
      Ob[(size_t)(sT + ty + j) * Ck + cT + tx] = __float2bfloat16(tile[tx][ty + j]);
    return;
  }

  // ---- ball query part ----
  int wave = (blockIdx.x - TRB) * 4 + (t >> 6);
  int lane = t & 63;
  int b = wave >> 11;                  // N1k = 2048
  int n = wave & (N1k - 1);
  int q = b * N1k + n;
  float qm = qmask[q];
  float qx = qxyz[q * 3 + 0];
  float qy = qxyz[q * 3 + 1];
  float qz = qxyz[q * 3 + 2];
  int cnt = 0, firstIdx = 0;
  int* myIdx = idxArr + (size_t)q * NSk;
  const float* Sx = sxyz + (size_t)b * N2k * 3;
  const float* Sm = smask + (size_t)b * N2k;
  if (qm > 0.f) {
    unsigned long long lmlt = (1ull << lane) - 1ull;
    float cx[4], cy[4], cz[4], cm[4];
    #pragma unroll
    for (int u = 0; u < 4; ++u) {
      int s = u * 64 + lane;
      cx[u] = Sx[3 * s]; cy[u] = Sx[3 * s + 1]; cz[u] = Sx[3 * s + 2];
      cm[u] = Sm[s];
    }
    for (int s0 = 0; s0 < N2k && cnt < NSk; s0 += 256) {
      float nx[4], ny[4], nz[4], nm[4];
      #pragma unroll
      for (int u = 0; u < 4; ++u) {
        int sp = s0 + 256 + u * 64 + lane;
        sp = (sp < N2k) ? sp : 0;      // clamped, unconditional prefetch
        nx[u] = Sx[3 * sp]; ny[u] = Sx[3 * sp + 1]; nz[u] = Sx[3 * sp + 2];
        nm[u] = Sm[sp];
      }
      #pragma unroll
      for (int u = 0; u < 4; ++u) {
        float dx = qx - cx[u], dy = qy - cy[u], dz = qz - cz[u];
        // match numpy association: (dx^2 + dy^2) + dz^2, no FMA contraction
        float d2 = __fadd_rn(__fadd_rn(__fmul_rn(dx, dx), __fmul_rn(dy, dy)),
                             __fmul_rn(dz, dz));
        bool valid = (d2 < 0.04f) && (cm[u] > 0.f);
        unsigned long long m = __ballot(valid);
        if (cnt == 0 && m != 0ull) firstIdx = s0 + u * 64 + (int)__builtin_ctzll(m);
        int p = cnt + (int)__popcll(m & lmlt);
        if (valid && p < NSk) myIdx[p] = s0 + u * 64 + lane;
        cnt += (int)__popcll(m);
      }
      #pragma unroll
      for (int u = 0; u < 4; ++u) {
        cx[u] = nx[u]; cy[u] = ny[u]; cz[u] = nz[u]; cm[u] = nm[u];
      }
    }
    if (cnt > NSk) cnt = NSk;
  }
  for (int p = cnt + lane; p < NSk; p += 64) myIdx[p] = firstIdx;
  if (lane == 0) cntArr[q] = cnt;
}

// ---------------------------------------------------------------------------
// K1: main aggregation (R4-proven). Block = 192 threads = 2 groups x 96; each
// group handles one query per "it"; 2 its -> 4 queries/block -> 2048 blocks.
// b = blockIdx&3 pins XCDs (round-robin dispatch) to one batch's Ftr slice.
// Thread j of a group owns channels {j, j+96, j+192} (all share rel axis j%3).
//  a2[c] = sum_k F[idx_k][c] * rel[k][c%3]                (unmasked, for gse)
//  a1[c] = sum_k F[idx_k][c] * rel[k][c%3] * fm[k]        (masked)
//  U[b,n,c] = a1 / sum_k fm[k]   (stored bf16)
// Per-(b,c) sums (gse, sumU, sumU2) via cross-group LDS merge + atomics.
// ---------------------------------------------------------------------------
__global__ __launch_bounds__(192, 6) void k_aggregate(
    const bf16* __restrict__ Ftr, const float* __restrict__ qxyz,
    const float* __restrict__ sxyz, const float* __restrict__ qmask,
    const int* __restrict__ idxArr, const int* __restrict__ cntArr,
    bf16* __restrict__ U, float* __restrict__ sumS2,
    float* __restrict__ sumU, float* __restrict__ sumU2) {
  __shared__ int   sidx[2][NSk];
  __shared__ float srel[2][NSk][3];
  __shared__ float srelm[2][NSk][3];
  __shared__ float sfinv[2];
  __shared__ float red[9][96];

  int b     = blockIdx.x & 3;
  int nbase = (blockIdx.x >> 2) * 4;    // 512 blocks per batch, 4 queries each
  int g = threadIdx.x / 96;
  int j = threadIdx.x % 96;
  int a = j % 3;

  float sS2[3]  = {0.f, 0.f, 0.f};
  float sUa[3]  = {0.f, 0.f, 0.f};
  float sU2a[3] = {0.f, 0.f, 0.f};

  const bf16* Fb = Ftr + (size_t)b * N2k * Ck;

  for (int it = 0; it < 2; ++it) {
    int n = nbase + it * 2 + g;
    int q = b * N1k + n;
    __syncthreads();
    if (j < NSk) {
      int k = j;
      int i = idxArr[(size_t)q * NSk + k];
      sidx[g][k] = i;
      float qx = qxyz[q * 3 + 0], qy = qxyz[q * 3 + 1], qz = qxyz[q * 3 + 2];
      float sx = sxyz[(b * N2k + i) * 3 + 0];
      float sy = sxyz[(b * N2k + i) * 3 + 1];
      float sz = sxyz[(b * N2k + i) * 3 + 2];
      float rx = (sx - qx) / 0.2f;
      float ry = (sy - qy) / 0.2f;
      float rz = (sz - qz) / 0.2f;
      float qmv = qmask[q];
      int fnd = cntArr[q];
      float fmk = (qmv > 0.f) ? ((k < fnd) ? 1.f : 0.f) : 1.f;
      srel[g][k][0] = rx; srel[g][k][1] = ry; srel[g][k][2] = rz;
      srelm[g][k][0] = rx * fmk; srelm[g][k][1] = ry * fmk; srelm[g][k][2] = rz * fmk;
      if (k == 0) {
        float fmsum = (qmv > 0.f) ? (float)fnd : (float)NSk;
        sfinv[g] = (fmsum > 0.f) ? (1.f / fmsum) : 0.f;
      }
    }
    __syncthreads();

    float a1[3] = {0.f, 0.f, 0.f};
    float a2[3] = {0.f, 0.f, 0.f};
    #pragma unroll 8
    for (int k = 0; k < NSk; ++k) {
      const bf16* row = Fb + (size_t)sidx[g][k] * Ck;
      float f0 = __bfloat162float(row[j]);
      float f1 = __bfloat162float(row[j + 96]);
      float f2 = __bfloat162float(row[j + 192]);
      float r  = srel[g][k][a];
      float rm = srelm[g][k][a];
      a2[0] = fmaf(f0, r, a2[0]);
      a2[1] = fmaf(f1, r, a2[1]);
      a2[2] = fmaf(f2, r, a2[2]);
      a1[0] = fmaf(f0, rm, a1[0]);
      a1[1] = fmaf(f1, rm, a1[1]);
      a1[2] = fmaf(f2, rm, a1[2]);
    }
    float finv = sfinv[g];
    float u0 = a1[0] * finv, u1 = a1[1] * finv, u2 = a1[2] * finv;
    bf16* Urow = U + (size_t)q * Ck;
    Urow[j]       = __float2bfloat16(u0);
    Urow[j + 96]  = __float2bfloat16(u1);
    Urow[j + 192] = __float2bfloat16(u2);
    sS2[0] += a2[0]; sS2[1] += a2[1]; sS2[2] += a2[2];
    sUa[0] += u0;    sUa[1] += u1;    sUa[2] += u2;
    sU2a[0] += u0 * u0; sU2a[1] += u1 * u1; sU2a[2] += u2 * u2;
  }

  // cross-group merge in LDS, then one set of atomics from group 0
  __syncthreads();
  if (g == 1) {
    red[0][j] = sS2[0];  red[1][j] = sS2[1];  red[2][j] = sS2[2];
    red[3][j] = sUa[0];  red[4][j] = sUa[1];  red[5][j] = sUa[2];
    red[6][j] = sU2a[0]; red[7][j] = sU2a[1]; red[8][j] = sU2a[2];
  }
  __syncthreads();
  if (g == 0) {
    float* pS2 = sumS2 + b * Ck;
    float* pU  = sumU  + b * Ck;
    float* pU2 = sumU2 + b * Ck;
    atomicAdd(&pS2[j],       sS2[0]  + red[0][j]);
    atomicAdd(&pS2[j + 96],  sS2[1]  + red[1][j]);
    atomicAdd(&pS2[j + 192], sS2[2]  + red[2][j]);
    atomicAdd(&pU[j],        sUa[0]  + red[3][j]);
    atomicAdd(&pU[j + 96],   sUa[1]  + red[4][j]);
    atomicAdd(&pU[j + 192],  sUa[2]  + red[5][j]);
    atomicAdd(&pU2[j],       sU2a[0] + red[6][j]);
    atomicAdd(&pU2[j + 96],  sU2a[1] + red[7][j]);
    atomicAdd(&pU2[j + 192], sU2a[2] + red[8][j]);
  }
}

// ---------------------------------------------------------------------------
// K2 (fused): finalize + inline excite. Each block recomputes the tiny SE MLP
// from the completed sums (w1/w2 are L2-hot), then transposes its U tile
// [B,N1,C] bf16 -> out [B,C,N1] fp32 applying relu(scale*u + bias).
// ---------------------------------------------------------------------------
__global__ __launch_bounds__(256) void k_fin(
    const bf16* __restrict__ U, const float* __restrict__ sums,
    const float* __restrict__ w1, const float* __restrict__ w2,
    const float* __restrict__ gamma, const float* __restrict__ beta,
    float* __restrict__ out) {
  __shared__ float tile[32][33];
  __shared__ float gse[Bk][Ck];
  __shared__ float hid[Bk * 18];
  __shared__ float sA[32], sB[32];

  int b  = blockIdx.z;
  int cT = blockIdx.y * 32, nT = blockIdx.x * 32;
  int tx = threadIdx.x, ty = threadIdx.y;  // 32 x 8
  int t = ty * 32 + tx;

  const bf16* Ub = U + (size_t)b * N1k * Ck;
  #pragma unroll
  for (int j = 0; j < 32; j += 8)
    tile[ty + j][tx] = __bfloat162float(Ub[(size_t)(nT + ty + j) * Ck + cT + tx]);

  for (int i = t; i < Bk * Ck; i += 256) gse[i / Ck][i % Ck] = sums[i] * (1.f / 65536.f);
  __syncthreads();

  if (t < Bk * 18) {                   // hid = relu(gse @ w1.T)
    int bb = t / 18, h = t % 18;
    const float* w1r = w1 + h * Ck;
    float s = 0.f;
    #pragma unroll 4
    for (int c = 0; c < Ck; ++c) s = fmaf(gse[bb][c], w1r[c], s);
    hid[t] = s > 0.f ? s : 0.f;
  }
  __syncthreads();
  if (t < 32) {                        // excite + LN fold for this block's channels
    int c = cT + t;
    const float* sumU  = sums + Bk * Ck;
    const float* sumU2 = sums + 2 * Bk * Ck;
    float m = 0.f, m2 = 0.f, eb_my = 0.f;
    #pragma unroll
    for (int bb = 0; bb < Bk; ++bb) {
      float s = 0.f;
      #pragma unroll
      for (int h = 0; h < 18; ++h) s += hid[bb * 18 + h] * w2[c * 18 + h];
      float e = 1.f / (1.f + expf(-s));
      if (bb == b) eb_my = e;
      m  += e * sumU[bb * Ck + c];
      m2 += e * e * sumU2[bb * Ck + c];
    }
    float mean = m * (1.f / 8192.f);
    float var  = m2 * (1.f / 8192.f) - mean * mean;
    float rsig = rsqrtf(var + 1e-5f);
    float gc = gamma[c];
    sA[t] = gc * rsig * eb_my;
    sB[t] = beta[c] - gc * rsig * mean;
  }
  __syncthreads();

  float* Ob = out + (size_t)b * Ck * N1k;
  #pragma unroll
  for (int j = 0; j < 32; j += 8) {
    int c = cT + ty + j;
    float v = sA[ty + j] * tile[tx][ty + j] + sB[ty + j];
    Ob[(size_t)c * N1k + nT + tx] = v > 0.f ? v : 0.f;
  }
}

// ---------------------------------------------------------------------------
extern "C" void kernel_launch(void* const* d_in, const int* in_sizes, int n_in,
                              void* d_out, int out_size, void* d_ws, size_t ws_size,
                              hipStream_t stream) {
  const float* qxyz  = (const float*)d_in[0];
  const float* sxyz  = (const float*)d_in[1];
  const float* qm    = (const float*)d_in[2];
  const float* sm    = (const float*)d_in[3];
  const float* F     = (const float*)d_in[4];
  const float* w1    = (const float*)d_in[5];
  const float* w2    = (const float*)d_in[6];
  const float* gamma = (const float*)d_in[7];
  const float* beta  = (const float*)d_in[8];

  char* ws = (char*)d_ws;
  size_t off = 0;
  auto alloc = [&](size_t bytes) {
    off = (off + 255) & ~(size_t)255;
    void* p = ws + off;
    off += bytes;
    return p;
  };
  bf16*  Ftr    = (bf16*) alloc(sizeof(bf16)  * (size_t)Bk * N2k * Ck);
  bf16*  U      = (bf16*) alloc(sizeof(bf16)  * (size_t)Bk * N1k * Ck);
  int*   idxArr = (int*)  alloc(sizeof(int)   * (size_t)Bk * N1k * NSk);
  int*   cntArr = (int*)  alloc(sizeof(int)   * (size_t)Bk * N1k);
  float* sums   = (float*)alloc(sizeof(float) * 3 * Bk * Ck);
  float* sumS2 = sums;
  float* sumU  = sums + Bk * Ck;
  float* sumU2 = sums + 2 * Bk * Ck;

  k_pre<<<TRB + Bk * (N1k / 4), 256, 0, stream>>>(F, sxyz, sm, qxyz, qm, Ftr,
                                                  idxArr, cntArr, sums);
  k_aggregate<<<Bk * (N1k / 4), 192, 0, stream>>>(Ftr, qxyz, sxyz, qm, idxArr, cntArr,
                                                  U, sumS2, sumU, sumU2);
  k_fin<<<dim3(N1k / 32, Ck / 32, Bk), dim3(32, 8), 0, stream>>>(U, sums, w1, w2,
                                                                 gamma, beta,
                                                                 (float*)d_out);
}

// Round 7
// 69.294 us; speedup vs baseline: 1.6893x; 1.3198x over previous
//
#include <hip/hip_runtime.h>
#include <hip/hip_bf16.h>
#include <cstdint>
#include <cstddef>

static constexpr int Bk  = 4;
static constexpr int N1k = 2048;
static constexpr int N2k = 8192;
static constexpr int Ck  = 288;
static constexpr int NSk = 32;
static constexpr int TRB = (N2k / 32) * (Ck / 32) * Bk;   // 9216 transpose blocks

typedef __hip_bfloat16 bf16;

// ---------------------------------------------------------------------------
// K0 (heterogeneous grid): blocks [0,TRB) transpose support_features
// [B,C,N2] fp32 -> Ftr [B,N2,C] bf16 (+ block 0 zeroes sums); blocks
// [TRB, TRB+2048) run the masked ball query (wave per query, 4 pts/lane/iter
// with scalar prefetch). The two jobs are independent: BQ (latency-bound)
// overlaps the transpose's HBM stream.
// ---------------------------------------------------------------------------
__global__ __launch_bounds__(256) void k_pre(
    const float* __restrict__ F, const float* __restrict__ sxyz,
    const float* __restrict__ smask, const float* __restrict__ qxyz,
    const float* __restrict__ qmask, bf16* __restrict__ Ftr,
    int* __restrict__ idxArr, int* __restrict__ cntArr,
    float* __restrict__ sums) {
  __shared__ float tile[32][33];
  int t = threadIdx.x;

  if (blockIdx.x < TRB) {
    // ---- transpose part ----
    int i  = blockIdx.x;
    int sT = (i & 255) * 32;
    int yz = i >> 8;
    int cT = (yz % 9) * 32;
    int b  = yz / 9;
    int tx = t & 31, ty = t >> 5;      // 32 x 8
    const float* Fb = F + (size_t)b * Ck * N2k;
    #pragma unroll
    for (int j = 0; j < 32; j += 8)
      tile[ty + j][tx] = Fb[(size_t)(cT + ty + j) * N2k + sT + tx];
    if (i == 0) {
      for (int k = t; k < 3 * Bk * Ck; k += 256) sums[k] = 0.f;
    }
    __syncthreads();
    bf16* Ob = Ftr + (size_t)b * N2k * Ck;
    #pragma unroll
    for (int j = 0; j < 32; j += 8)
      Ob[(size_t)(sT + ty + j) * Ck + cT + tx] = __float2bfloat16(tile[tx][ty + j]);
    return;
  }

  // ---- ball query part ----
  int wave = (blockIdx.x - TRB) * 4 + (t >> 6);
  int lane = t & 63;
  int b = wave >> 11;                  // N1k = 2048
  int n = wave & (N1k - 1);
  int q = b * N1k + n;
  float qm = qmask[q];
  float qx = qxyz[q * 3 + 0];
  float qy = qxyz[q * 3 + 1];
  float qz = qxyz[q * 3 + 2];
  int cnt = 0, firstIdx = 0;
  int* myIdx = idxArr + (size_t)q * NSk;
  const float* Sx = sxyz + (size_t)b * N2k * 3;
  const float* Sm = smask + (size_t)b * N2k;
  if (qm > 0.f) {
    unsigned long long lmlt = (1ull << lane) - 1ull;
    float cx[4], cy[4], cz[4], cm[4];
    #pragma unroll
    for (int u = 0; u < 4; ++u) {
      int s = u * 64 + lane;
      cx[u] = Sx[3 * s]; cy[u] = Sx[3 * s + 1]; cz[u] = Sx[3 * s + 2];
      cm[u] = Sm[s];
    }
    for (int s0 = 0; s0 < N2k && cnt < NSk; s0 += 256) {
      float nx[4], ny[4], nz[4], nm[4];
      #pragma unroll
      for (int u = 0; u < 4; ++u) {
        int sp = s0 + 256 + u * 64 + lane;
        sp = (sp < N2k) ? sp : 0;      // clamped, unconditional prefetch
        nx[u] = Sx[3 * sp]; ny[u] = Sx[3 * sp + 1]; nz[u] = Sx[3 * sp + 2];
        nm[u] = Sm[sp];
      }
      #pragma unroll
      for (int u = 0; u < 4; ++u) {
        float dx = qx - cx[u], dy = qy - cy[u], dz = qz - cz[u];
        // match numpy association: (dx^2 + dy^2) + dz^2, no FMA contraction
        float d2 = __fadd_rn(__fadd_rn(__fmul_rn(dx, dx), __fmul_rn(dy, dy)),
                             __fmul_rn(dz, dz));
        bool valid = (d2 < 0.04f) && (cm[u] > 0.f);
        unsigned long long m = __ballot(valid);
        if (cnt == 0 && m != 0ull) firstIdx = s0 + u * 64 + (int)__builtin_ctzll(m);
        int p = cnt + (int)__popcll(m & lmlt);
        if (valid && p < NSk) myIdx[p] = s0 + u * 64 + lane;
        cnt += (int)__popcll(m);
      }
      #pragma unroll
      for (int u = 0; u < 4; ++u) {
        cx[u] = nx[u]; cy[u] = ny[u]; cz[u] = nz[u]; cm[u] = nm[u];
      }
    }
    if (cnt > NSk) cnt = NSk;
  }
  for (int p = cnt + lane; p < NSk; p += 64) myIdx[p] = firstIdx;
  if (lane == 0) cntArr[q] = cnt;
}

// ---------------------------------------------------------------------------
// K1: main aggregation (R4-proven). Block = 192 threads = 2 groups x 96; each
// group handles one query per "it"; 2 its -> 4 queries/block -> 2048 blocks.
// b = blockIdx&3 pins XCDs (round-robin dispatch) to one batch's Ftr slice.
// Thread j of a group owns channels {j, j+96, j+192} (all share rel axis j%3).
//  a2[c] = sum_k F[idx_k][c] * rel[k][c%3]                (unmasked, for gse)
//  a1[c] = sum_k F[idx_k][c] * rel[k][c%3] * fm[k]        (masked)
//  U[b,n,c] = a1 / sum_k fm[k]   (stored bf16)
// Per-(b,c) sums (gse, sumU, sumU2) via cross-group LDS merge + atomics.
// ---------------------------------------------------------------------------
__global__ __launch_bounds__(192, 6) void k_aggregate(
    const bf16* __restrict__ Ftr, const float* __restrict__ qxyz,
    const float* __restrict__ sxyz, const float* __restrict__ qmask,
    const int* __restrict__ idxArr, const int* __restrict__ cntArr,
    bf16* __restrict__ U, float* __restrict__ sumS2,
    float* __restrict__ sumU, float* __restrict__ sumU2) {
  __shared__ int   sidx[2][NSk];
  __shared__ float srel[2][NSk][3];
  __shared__ float srelm[2][NSk][3];
  __shared__ float sfinv[2];
  __shared__ float red[9][96];

  int b     = blockIdx.x & 3;
  int nbase = (blockIdx.x >> 2) * 4;    // 512 blocks per batch, 4 queries each
  int g = threadIdx.x / 96;
  int j = threadIdx.x % 96;
  int a = j % 3;

  float sS2[3]  = {0.f, 0.f, 0.f};
  float sUa[3]  = {0.f, 0.f, 0.f};
  float sU2a[3] = {0.f, 0.f, 0.f};

  const bf16* Fb = Ftr + (size_t)b * N2k * Ck;

  for (int it = 0; it < 2; ++it) {
    int n = nbase + it * 2 + g;
    int q = b * N1k + n;
    __syncthreads();
    if (j < NSk) {
      int k = j;
      int i = idxArr[(size_t)q * NSk + k];
      sidx[g][k] = i;
      float qx = qxyz[q * 3 + 0], qy = qxyz[q * 3 + 1], qz = qxyz[q * 3 + 2];
      float sx = sxyz[(b * N2k + i) * 3 + 0];
      float sy = sxyz[(b * N2k + i) * 3 + 1];
      float sz = sxyz[(b * N2k + i) * 3 + 2];
      float rx = (sx - qx) / 0.2f;
      float ry = (sy - qy) / 0.2f;
      float rz = (sz - qz) / 0.2f;
      float qmv = qmask[q];
      int fnd = cntArr[q];
      float fmk = (qmv > 0.f) ? ((k < fnd) ? 1.f : 0.f) : 1.f;
      srel[g][k][0] = rx; srel[g][k][1] = ry; srel[g][k][2] = rz;
      srelm[g][k][0] = rx * fmk; srelm[g][k][1] = ry * fmk; srelm[g][k][2] = rz * fmk;
      if (k == 0) {
        float fmsum = (qmv > 0.f) ? (float)fnd : (float)NSk;
        sfinv[g] = (fmsum > 0.f) ? (1.f / fmsum) : 0.f;
      }
    }
    __syncthreads();

    float a1[3] = {0.f, 0.f, 0.f};
    float a2[3] = {0.f, 0.f, 0.f};
    #pragma unroll 8
    for (int k = 0; k < NSk; ++k) {
      const bf16* row = Fb + (size_t)sidx[g][k] * Ck;
      float f0 = __bfloat162float(row[j]);
      float f1 = __bfloat162float(row[j + 96]);
      float f2 = __bfloat162float(row[j + 192]);
      float r  = srel[g][k][a];
      float rm = srelm[g][k][a];
      a2[0] = fmaf(f0, r, a2[0]);
      a2[1] = fmaf(f1, r, a2[1]);
      a2[2] = fmaf(f2, r, a2[2]);
      a1[0] = fmaf(f0, rm, a1[0]);
      a1[1] = fmaf(f1, rm, a1[1]);
      a1[2] = fmaf(f2, rm, a1[2]);
    }
    float finv = sfinv[g];
    float u0 = a1[0] * finv, u1 = a1[1] * finv, u2 = a1[2] * finv;
    bf16* Urow = U + (size_t)q * Ck;
    Urow[j]       = __float2bfloat16(u0);
    Urow[j + 96]  = __float2bfloat16(u1);
    Urow[j + 192] = __float2bfloat16(u2);
    sS2[0] += a2[0]; sS2[1] += a2[1]; sS2[2] += a2[2];
    sUa[0] += u0;    sUa[1] += u1;    sUa[2] += u2;
    sU2a[0] += u0 * u0; sU2a[1] += u1 * u1; sU2a[2] += u2 * u2;
  }

  // cross-group merge in LDS, then one set of atomics from group 0
  __syncthreads();
  if (g == 1) {
    red[0][j] = sS2[0];  red[1][j] = sS2[1];  red[2][j] = sS2[2];
    red[3][j] = sUa[0];  red[4][j] = sUa[1];  red[5][j] = sUa[2];
    red[6][j] = sU2a[0]; red[7][j] = sU2a[1]; red[8][j] = sU2a[2];
  }
  __syncthreads();
  if (g == 0) {
    float* pS2 = sumS2 + b * Ck;
    float* pU  = sumU  + b * Ck;
    float* pU2 = sumU2 + b * Ck;
    atomicAdd(&pS2[j],       sS2[0]  + red[0][j]);
    atomicAdd(&pS2[j + 96],  sS2[1]  + red[1][j]);
    atomicAdd(&pS2[j + 192], sS2[2]  + red[2][j]);
    atomicAdd(&pU[j],        sUa[0]  + red[3][j]);
    atomicAdd(&pU[j + 96],   sUa[1]  + red[4][j]);
    atomicAdd(&pU[j + 192],  sUa[2]  + red[5][j]);
    atomicAdd(&pU2[j],       sU2a[0] + red[6][j]);
    atomicAdd(&pU2[j + 96],  sU2a[1] + red[7][j]);
    atomicAdd(&pU2[j + 192], sU2a[2] + red[8][j]);
  }
}

// ---------------------------------------------------------------------------
// K2: gse -> MLP -> sigmoid excite, ONCE in a single block; fold excite + LN
// stats into per-(b,c) scaleA and per-c biasB.
// ---------------------------------------------------------------------------
__global__ __launch_bounds__(288) void k_excite(
    const float* __restrict__ sumS2, const float* __restrict__ sumU,
    const float* __restrict__ sumU2, const float* __restrict__ w1,
    const float* __restrict__ w2, const float* __restrict__ gamma,
    const float* __restrict__ beta, float* __restrict__ scaleA,
    float* __restrict__ biasB) {
  __shared__ float gse[Bk * Ck];
  __shared__ float hid[Bk * 18];
  int t = threadIdx.x;
  for (int i = t; i < Bk * Ck; i += 288) gse[i] = sumS2[i] * (1.f / 65536.f);
  __syncthreads();
  if (t < Bk * 18) {
    int b = t / 18, h = t % 18;
    float s = 0.f;
    for (int c = 0; c < Ck; ++c) s += gse[b * Ck + c] * w1[h * Ck + c];
    hid[t] = s > 0.f ? s : 0.f;
  }
  __syncthreads();
  if (t < Ck) {
    int c = t;
    float m = 0.f, m2 = 0.f;
    float eb[Bk];
    #pragma unroll
    for (int b = 0; b < Bk; ++b) {
      float s = 0.f;
      #pragma unroll
      for (int h = 0; h < 18; ++h) s += hid[b * 18 + h] * w2[c * 18 + h];
      float e = 1.f / (1.f + expf(-s));
      eb[b] = e;
      m  += e * sumU[b * Ck + c];
      m2 += e * e * sumU2[b * Ck + c];
    }
    float mean = m * (1.f / 8192.f);
    float ex2  = m2 * (1.f / 8192.f);
    float var  = ex2 - mean * mean;
    float rsig = rsqrtf(var + 1e-5f);
    float gc = gamma[c];
    #pragma unroll
    for (int b = 0; b < Bk; ++b) scaleA[b * Ck + c] = gc * rsig * eb[b];
    biasB[c] = beta[c] - gc * rsig * mean;
  }
}

// ---------------------------------------------------------------------------
// K3: finalize. Tiled transpose U [B,N1,C] bf16 -> out [B,C,N1] fp32 with
// out = relu(scaleA * u + biasB). scaleA/biasB precomputed by k_excite.
// ---------------------------------------------------------------------------
__global__ void k_finalize(const bf16* __restrict__ U, const float* __restrict__ scaleA,
                           const float* __restrict__ biasB, float* __restrict__ out) {
  __shared__ float tile[32][33];
  int b  = blockIdx.z;
  int cT = blockIdx.y * 32, nT = blockIdx.x * 32;
  int tx = threadIdx.x, ty = threadIdx.y;  // 32 x 8
  const bf16* Ub = U + (size_t)b * N1k * Ck;
  #pragma unroll
  for (int j = 0; j < 32; j += 8)
    tile[ty + j][tx] = __bfloat162float(Ub[(size_t)(nT + ty + j) * Ck + cT + tx]);
  __syncthreads();
  float* Ob = out + (size_t)b * Ck * N1k;
  #pragma unroll
  for (int j = 0; j < 32; j += 8) {
    int c = cT + ty + j;
    float v = scaleA[b * Ck + c] * tile[tx][ty + j] + biasB[c];
    Ob[(size_t)c * N1k + nT + tx] = v > 0.f ? v : 0.f;
  }
}

// ---------------------------------------------------------------------------
extern "C" void kernel_launch(void* const* d_in, const int* in_sizes, int n_in,
                              void* d_out, int out_size, void* d_ws, size_t ws_size,
                              hipStream_t stream) {
  const float* qxyz  = (const float*)d_in[0];
  const float* sxyz  = (const float*)d_in[1];
  const float* qm    = (const float*)d_in[2];
  const float* sm    = (const float*)d_in[3];
  const float* F     = (const float*)d_in[4];
  const float* w1    = (const float*)d_in[5];
  const float* w2    = (const float*)d_in[6];
  const float* gamma = (const float*)d_in[7];
  const float* beta  = (const float*)d_in[8];

  char* ws = (char*)d_ws;
  size_t off = 0;
  auto alloc = [&](size_t bytes) {
    off = (off + 255) & ~(size_t)255;
    void* p = ws + off;
    off += bytes;
    return p;
  };
  bf16*  Ftr    = (bf16*) alloc(sizeof(bf16)  * (size_t)Bk * N2k * Ck);
  bf16*  U      = (bf16*) alloc(sizeof(bf16)  * (size_t)Bk * N1k * Ck);
  int*   idxArr = (int*)  alloc(sizeof(int)   * (size_t)Bk * N1k * NSk);
  int*   cntArr = (int*)  alloc(sizeof(int)   * (size_t)Bk * N1k);
  float* sums   = (float*)alloc(sizeof(float) * 3 * Bk * Ck);
  float* sumS2 = sums;
  float* sumU  = sums + Bk * Ck;
  float* sumU2 = sums + 2 * Bk * Ck;
  float* scaleA = (float*)alloc(sizeof(float) * Bk * Ck);
  float* biasB  = (float*)alloc(sizeof(float) * Ck);

  k_pre<<<TRB + Bk * (N1k / 4), 256, 0, stream>>>(F, sxyz, sm, qxyz, qm, Ftr,
                                                  idxArr, cntArr, sums);
  k_aggregate<<<Bk * (N1k / 4), 192, 0, stream>>>(Ftr, qxyz, sxyz, qm, idxArr, cntArr,
                                                  U, sumS2, sumU, sumU2);
  k_excite<<<1, 288, 0, stream>>>(sumS2, sumU, sumU2, w1, w2, gamma, beta, scaleA, biasB);
  k_finalize<<<dim3(N1k / 32, Ck / 32, Bk), dim3(32, 8), 0, stream>>>(U, scaleA, biasB,
                                                                      (float*)d_out);
}